// Round 1
// baseline (1090.714 us; speedup 1.0000x reference)
//
#include <hip/hip_runtime.h>
#include <math.h>

#define T_TOK 4096
#define D_DIM 1024

typedef __attribute__((ext_vector_type(4))) float f32x4;
typedef __attribute__((ext_vector_type(8))) short s16x8;

__device__ __forceinline__ unsigned short f2bf(float f){
  union { float f; unsigned u; } v; v.f = f;
  unsigned r = v.u + 0x7FFFu + ((v.u >> 16) & 1u);   // RNE; inputs finite
  return (unsigned short)(r >> 16);
}

// ---------------- router: fp64 logits, argmax, w_t, aux-loss sums ----------------
__global__ __launch_bounds__(256) void router_kernel(
    const float* __restrict__ x, const float* __restrict__ gumbel,
    const float* __restrict__ rw, const float* __restrict__ rb,
    int* __restrict__ expert_id, float* __restrict__ wtok,
    double* __restrict__ prob_sums, int* __restrict__ counts)
{
  int wave = threadIdx.x >> 6, lane = threadIdx.x & 63;
  int t = blockIdx.x * 4 + wave;
  const float* xr = x + (size_t)t * D_DIM;
  double acc[8];
  #pragma unroll
  for (int e = 0; e < 8; e++) acc[e] = 0.0;
  #pragma unroll
  for (int i = 0; i < 16; i++){
    int d = i * 64 + lane;
    double xv = (double)xr[d];
    const float4* rwp = (const float4*)(rw + (size_t)d * 8);
    float4 r0 = rwp[0], r1 = rwp[1];
    acc[0] += xv * (double)r0.x; acc[1] += xv * (double)r0.y;
    acc[2] += xv * (double)r0.z; acc[3] += xv * (double)r0.w;
    acc[4] += xv * (double)r1.x; acc[5] += xv * (double)r1.y;
    acc[6] += xv * (double)r1.z; acc[7] += xv * (double)r1.w;
  }
  #pragma unroll
  for (int e = 0; e < 8; e++){
    #pragma unroll
    for (int off = 32; off; off >>= 1) acc[e] += __shfl_xor(acc[e], off);
  }
  // every lane holds full sums; do the scalar tail redundantly (no divergence)
  double logit[8], z[8];
  #pragma unroll
  for (int e = 0; e < 8; e++){
    logit[e] = acc[e] + (double)rb[e];
    z[e] = logit[e] + (double)gumbel[(size_t)t * 8 + e];
  }
  int amax = 0;
  #pragma unroll
  for (int e = 1; e < 8; e++) if (z[e] > z[amax]) amax = e;   // first-max like jnp.argmax
  float zm = (float)z[amax];
  float se = 0.f;
  #pragma unroll
  for (int e = 0; e < 8; e++) se += expf((float)z[e] - zm);
  float y = 1.f / se;                 // y_soft at argmax
  float w = (1.0f - y) + y;           // replicate ref fp32 arithmetic
  double lm = logit[0];
  #pragma unroll
  for (int e = 1; e < 8; e++) lm = fmax(lm, logit[e]);
  float p[8]; float ps = 0.f;
  #pragma unroll
  for (int e = 0; e < 8; e++){ p[e] = expf((float)(logit[e] - lm)); ps += p[e]; }
  float inv = 1.f / ps;

  __shared__ float sprob[4][8];
  if (lane == 0){
    expert_id[t] = amax; wtok[t] = w;
    atomicAdd(&counts[amax], 1);
    #pragma unroll
    for (int e = 0; e < 8; e++) sprob[wave][e] = p[e] * inv;
  }
  __syncthreads();
  if (threadIdx.x < 8){
    double s = (double)sprob[0][threadIdx.x] + (double)sprob[1][threadIdx.x]
             + (double)sprob[2][threadIdx.x] + (double)sprob[3][threadIdx.x];
    atomicAdd(&prob_sums[threadIdx.x], s);
  }
}

// ---------------- finalize: offsets/cursors + aux loss ----------------
__global__ void finalize_kernel(const double* __restrict__ prob_sums, const int* __restrict__ counts,
                                int* __restrict__ offsets, int* __restrict__ cursor,
                                float* __restrict__ aux_out)
{
  if (threadIdx.x == 0){
    int off = 0; double aux = 0.0;
    for (int e = 0; e < 8; e++){ offsets[e] = off; cursor[e] = off; off += counts[e]; }
    for (int e = 0; e < 8; e++){
      double imp = prob_sums[e] / 4096.0;
      double d = imp - 0.125;
      aux += d * d;
    }
    aux_out[0] = (float)(aux / 8.0);
  }
}

// ---------------- scatter: counting-sort tokens + x -> bf16 grouped ----------------
__global__ __launch_bounds__(256) void scatter_kernel(
    const float* __restrict__ x, const int* __restrict__ expert_id, const float* __restrict__ wtok,
    int* __restrict__ cursor, int* __restrict__ token_of, float* __restrict__ gw,
    unsigned short* __restrict__ Xg)
{
  int t = blockIdx.x;
  __shared__ int spos;
  if (threadIdx.x == 0){
    int e = expert_id[t];
    int p = atomicAdd(&cursor[e], 1);
    spos = p;
    token_of[p] = t; gw[p] = wtok[t];
  }
  __syncthreads();
  int pos = spos;
  float4 v = ((const float4*)(x + (size_t)t * D_DIM))[threadIdx.x];
  ushort4 o; o.x = f2bf(v.x); o.y = f2bf(v.y); o.z = f2bf(v.z); o.w = f2bf(v.w);
  ((ushort4*)(Xg + (size_t)pos * D_DIM))[threadIdx.x] = o;
}

// ---------------- grouped GEMM: C = act(A[group] @ W[e] + bias[e]) ----------------
// 128x128 tile, BK=32, 256 threads (4 waves, 2x2 of 64x64), mfma 16x16x32 bf16.
// A: bf16 row-major T x K (grouped rows). W: fp32 [E][K][N] (converted to bf16 in staging).
// LDS: sA row-major [128][32] pad->40; sB n-major [128n][32k] pad->40 (transposed at write).
template<int K, int N, int PASS2>
__global__ __launch_bounds__(256) void ffn_gemm(
    const unsigned short* __restrict__ A,
    const float* __restrict__ W,
    const float* __restrict__ bias,
    const int* __restrict__ counts, const int* __restrict__ offsets,
    const int* __restrict__ token_of, const float* __restrict__ gw,
    unsigned short* __restrict__ Hout,   // pass1 output (bf16, gelu)
    float* __restrict__ Fout)            // pass2 output (fp32, scattered rows, *w +b2)
{
  int e = blockIdx.z;
  int cnt = counts[e];
  int by = blockIdx.y;
  if (by * 128 >= cnt) return;            // uniform early-exit
  int offs = offsets[e];
  int bx = blockIdx.x;
  int tid = threadIdx.x;
  int lane = tid & 63, wave = tid >> 6;
  int wm = wave & 1, wn = wave >> 1;

  __shared__ unsigned short sA[128 * 40];
  __shared__ unsigned short sB[128 * 40];

  const float* wp = W + (size_t)e * K * N + (size_t)bx * 128;

  // A staging: 4 threads/row, 8 bf16 (16B) each; 2 half-tiles of 64 rows
  int rowA = tid >> 2, kaoff = (tid & 3) * 8;
  size_t aAddr[2];
  #pragma unroll
  for (int h = 0; h < 2; h++){
    int pos = offs + by * 128 + rowA + h * 64;
    if (pos > T_TOK - 1) pos = T_TOK - 1;          // clamp; masked at store
    aAddr[h] = (size_t)pos * K + kaoff;
  }
  // B staging: thread owns (k0..k0+3, n) for 4 n's -> 4 ds_write_b64, conflict-free
  int kb0 = (tid & 7) * 4, nb = tid >> 3;

  f32x4 accv[4][4];
  #pragma unroll
  for (int mi = 0; mi < 4; mi++)
    #pragma unroll
    for (int ni = 0; ni < 4; ni++) accv[mi][ni] = (f32x4){0.f, 0.f, 0.f, 0.f};

  uint4 ra[2];
  float rbv[4][4];

  auto loadA = [&](int kt){
    #pragma unroll
    for (int h = 0; h < 2; h++)
      ra[h] = *(const uint4*)(A + aAddr[h] + kt * 32);
  };
  auto loadB = [&](int kt){
    #pragma unroll
    for (int h = 0; h < 4; h++){
      const float* bp = wp + (size_t)(kt * 32 + kb0) * N + nb + h * 32;
      #pragma unroll
      for (int j = 0; j < 4; j++) rbv[h][j] = bp[(size_t)j * N];
    }
  };

  loadA(0); loadB(0);

  int col = lane & 15, quad = lane >> 4;
  const int NK = K / 32;
  for (int kt = 0; kt < NK; ++kt){
    __syncthreads();
    #pragma unroll
    for (int h = 0; h < 2; h++)
      *(uint4*)&sA[(rowA + h * 64) * 40 + kaoff] = ra[h];
    #pragma unroll
    for (int h = 0; h < 4; h++){
      unsigned lo = (unsigned)f2bf(rbv[h][0]) | ((unsigned)f2bf(rbv[h][1]) << 16);
      unsigned hi = (unsigned)f2bf(rbv[h][2]) | ((unsigned)f2bf(rbv[h][3]) << 16);
      uint2 u; u.x = lo; u.y = hi;
      *(uint2*)&sB[(nb + h * 32) * 40 + kb0] = u;
    }
    __syncthreads();
    if (kt + 1 < NK){ loadA(kt + 1); loadB(kt + 1); }   // reg prefetch overlaps MFMA
    s16x8 af[4], bf[4];
    #pragma unroll
    for (int mi = 0; mi < 4; mi++)
      af[mi] = *(const s16x8*)&sA[(wm * 64 + mi * 16 + col) * 40 + quad * 8];
    #pragma unroll
    for (int ni = 0; ni < 4; ni++)
      bf[ni] = *(const s16x8*)&sB[(wn * 64 + ni * 16 + col) * 40 + quad * 8];
    #pragma unroll
    for (int mi = 0; mi < 4; mi++)
      #pragma unroll
      for (int ni = 0; ni < 4; ni++)
        accv[mi][ni] = __builtin_amdgcn_mfma_f32_16x16x32_bf16(af[mi], bf[ni], accv[mi][ni], 0, 0, 0);
  }

  float bv[4];
  #pragma unroll
  for (int ni = 0; ni < 4; ni++)
    bv[ni] = bias[(size_t)e * N + bx * 128 + wn * 64 + ni * 16 + col];

  if (PASS2 == 0){
    #pragma unroll
    for (int mi = 0; mi < 4; mi++){
      int rbase = by * 128 + wm * 64 + mi * 16 + quad * 4;
      #pragma unroll
      for (int r = 0; r < 4; r++){
        int row = rbase + r;
        if (row < cnt){
          size_t orow = (size_t)(offs + row) * N + bx * 128 + wn * 64 + col;
          #pragma unroll
          for (int ni = 0; ni < 4; ni++){
            float v = accv[mi][ni][r] + bv[ni];
            float g = 0.5f * v * (1.0f + erff(v * 0.70710678118654752f));  // exact gelu
            Hout[orow + ni * 16] = f2bf(g);
          }
        }
      }
    }
  } else {
    #pragma unroll
    for (int mi = 0; mi < 4; mi++){
      int rbase = by * 128 + wm * 64 + mi * 16 + quad * 4;
      #pragma unroll
      for (int r = 0; r < 4; r++){
        int row = rbase + r;
        if (row < cnt){
          int pos = offs + row;
          int tok = token_of[pos];
          float wgt = gw[pos];
          size_t orow = (size_t)tok * N + bx * 128 + wn * 64 + col;
          #pragma unroll
          for (int ni = 0; ni < 4; ni++){
            float v = (accv[mi][ni][r] + bv[ni]) * wgt;
            Fout[orow + ni * 16] = v;
          }
        }
      }
    }
  }
}

extern "C" void kernel_launch(void* const* d_in, const int* in_sizes, int n_in,
                              void* d_out, int out_size, void* d_ws, size_t ws_size,
                              hipStream_t stream)
{
  const float* x      = (const float*)d_in[0];
  const float* gumbel = (const float*)d_in[1];
  const float* rw     = (const float*)d_in[2];
  const float* rb     = (const float*)d_in[3];
  const float* w1     = (const float*)d_in[4];
  const float* b1     = (const float*)d_in[5];
  const float* w2     = (const float*)d_in[6];
  const float* b2     = (const float*)d_in[7];
  float* out = (float*)d_out;

  char* ws = (char*)d_ws;
  double* prob_sums = (double*)(ws + 0);     // 64 B
  int* counts    = (int*)(ws + 64);
  int* offsets   = (int*)(ws + 96);
  int* cursor    = (int*)(ws + 128);
  int* expert_id = (int*)(ws + 256);                    // 16 KB
  float* wtok    = (float*)(ws + 256 + 16384);          // 16 KB
  int* token_of  = (int*)(ws + 256 + 2 * 16384);        // 16 KB
  float* gw      = (float*)(ws + 256 + 3 * 16384);      // 16 KB -> ends at 65792
  unsigned short* Xg     = (unsigned short*)(ws + 65792);             // 8 MB bf16
  unsigned short* hidden = (unsigned short*)(ws + 65792 + 8388608);   // 33.5 MB bf16

  hipMemsetAsync(ws, 0, 256, stream);   // zero atomic accumulators (capture-safe)

  router_kernel<<<1024, 256, 0, stream>>>(x, gumbel, rw, rb, expert_id, wtok, prob_sums, counts);
  finalize_kernel<<<1, 64, 0, stream>>>(prob_sums, counts, offsets, cursor, out + 4194304);
  scatter_kernel<<<4096, 256, 0, stream>>>(x, expert_id, wtok, cursor, token_of, gw, Xg);
  // hidden = gelu(Xg @ w1[e] + b1[e])   (M=cnt_e, N=4096, K=1024)
  ffn_gemm<1024, 4096, 0><<<dim3(32, 32, 8), 256, 0, stream>>>(
      Xg, w1, b1, counts, offsets, nullptr, nullptr, hidden, nullptr);
  // out[tok] = w_t * (hidden @ w2[e] + b2[e])   (M=cnt_e, N=1024, K=4096)
  ffn_gemm<4096, 1024, 1><<<dim3(8, 32, 8), 256, 0, stream>>>(
      hidden, w2, b2, counts, offsets, token_of, gw, nullptr, out);
}

// Round 2
// 591.377 us; speedup vs baseline: 1.8444x; 1.8444x over previous
//
#include <hip/hip_runtime.h>
#include <math.h>

#define T_TOK 4096
#define D_DIM 1024

typedef __attribute__((ext_vector_type(4))) float f32x4;
typedef __attribute__((ext_vector_type(8))) short s16x8;

__device__ __forceinline__ unsigned short f2bf(float f){
  union { float f; unsigned u; } v; v.f = f;
  unsigned r = v.u + 0x7FFFu + ((v.u >> 16) & 1u);   // RNE; inputs finite
  return (unsigned short)(r >> 16);
}

__device__ __forceinline__ void gld_lds16(const unsigned short* g, unsigned short* l){
  __builtin_amdgcn_global_load_lds(
      (const __attribute__((address_space(1))) unsigned int*)g,
      (__attribute__((address_space(3))) unsigned int*)l, 16, 0, 0);
}

// ---------------- router: fp64 logits, argmax, w_t, aux-loss sums ----------------
__global__ __launch_bounds__(256) void router_kernel(
    const float* __restrict__ x, const float* __restrict__ gumbel,
    const float* __restrict__ rw, const float* __restrict__ rb,
    int* __restrict__ expert_id, float* __restrict__ wtok,
    double* __restrict__ prob_sums, int* __restrict__ counts)
{
  int wave = threadIdx.x >> 6, lane = threadIdx.x & 63;
  int t = blockIdx.x * 4 + wave;
  const float* xr = x + (size_t)t * D_DIM;
  double acc[8];
  #pragma unroll
  for (int e = 0; e < 8; e++) acc[e] = 0.0;
  #pragma unroll
  for (int i = 0; i < 16; i++){
    int d = i * 64 + lane;
    double xv = (double)xr[d];
    const float4* rwp = (const float4*)(rw + (size_t)d * 8);
    float4 r0 = rwp[0], r1 = rwp[1];
    acc[0] += xv * (double)r0.x; acc[1] += xv * (double)r0.y;
    acc[2] += xv * (double)r0.z; acc[3] += xv * (double)r0.w;
    acc[4] += xv * (double)r1.x; acc[5] += xv * (double)r1.y;
    acc[6] += xv * (double)r1.z; acc[7] += xv * (double)r1.w;
  }
  #pragma unroll
  for (int e = 0; e < 8; e++){
    #pragma unroll
    for (int off = 32; off; off >>= 1) acc[e] += __shfl_xor(acc[e], off);
  }
  double logit[8], z[8];
  #pragma unroll
  for (int e = 0; e < 8; e++){
    logit[e] = acc[e] + (double)rb[e];
    z[e] = logit[e] + (double)gumbel[(size_t)t * 8 + e];
  }
  int amax = 0;
  #pragma unroll
  for (int e = 1; e < 8; e++) if (z[e] > z[amax]) amax = e;   // first-max like jnp.argmax
  float zm = (float)z[amax];
  float se = 0.f;
  #pragma unroll
  for (int e = 0; e < 8; e++) se += expf((float)z[e] - zm);
  float y = 1.f / se;                 // y_soft at argmax
  float w = (1.0f - y) + y;           // replicate ref fp32 arithmetic
  double lm = logit[0];
  #pragma unroll
  for (int e = 1; e < 8; e++) lm = fmax(lm, logit[e]);
  float p[8]; float ps = 0.f;
  #pragma unroll
  for (int e = 0; e < 8; e++){ p[e] = expf((float)(logit[e] - lm)); ps += p[e]; }
  float inv = 1.f / ps;

  __shared__ float sprob[4][8];
  if (lane == 0){
    expert_id[t] = amax; wtok[t] = w;
    atomicAdd(&counts[amax], 1);
    #pragma unroll
    for (int e = 0; e < 8; e++) sprob[wave][e] = p[e] * inv;
  }
  __syncthreads();
  if (threadIdx.x < 8){
    double s = (double)sprob[0][threadIdx.x] + (double)sprob[1][threadIdx.x]
             + (double)sprob[2][threadIdx.x] + (double)sprob[3][threadIdx.x];
    atomicAdd(&prob_sums[threadIdx.x], s);
  }
}

// ---------------- finalize: offsets/cursors + aux loss ----------------
__global__ void finalize_kernel(const double* __restrict__ prob_sums, const int* __restrict__ counts,
                                int* __restrict__ offsets, int* __restrict__ cursor,
                                float* __restrict__ aux_out)
{
  if (threadIdx.x == 0){
    int off = 0; double aux = 0.0;
    for (int e = 0; e < 8; e++){ offsets[e] = off; cursor[e] = off; off += counts[e]; }
    for (int e = 0; e < 8; e++){
      double imp = prob_sums[e] / 4096.0;
      double d = imp - 0.125;
      aux += d * d;
    }
    aux_out[0] = (float)(aux / 8.0);
  }
}

// ---------------- scatter: counting-sort tokens + x -> bf16 grouped ----------------
__global__ __launch_bounds__(256) void scatter_kernel(
    const float* __restrict__ x, const int* __restrict__ expert_id, const float* __restrict__ wtok,
    int* __restrict__ cursor, int* __restrict__ token_of, float* __restrict__ gw,
    unsigned short* __restrict__ Xg)
{
  int t = blockIdx.x;
  __shared__ int spos;
  if (threadIdx.x == 0){
    int e = expert_id[t];
    int p = atomicAdd(&cursor[e], 1);
    spos = p;
    token_of[p] = t; gw[p] = wtok[t];
  }
  __syncthreads();
  int pos = spos;
  float4 v = ((const float4*)(x + (size_t)t * D_DIM))[threadIdx.x];
  ushort4 o; o.x = f2bf(v.x); o.y = f2bf(v.y); o.z = f2bf(v.z); o.w = f2bf(v.w);
  ((ushort4*)(Xg + (size_t)pos * D_DIM))[threadIdx.x] = o;
}

// ---------------- weight transpose+convert: fp32 [E][K][N] -> bf16 [E][N][K] ----------------
// 64x64 tiles via padded LDS; coalesced read (float4 along N) and write (16B along K).
__global__ __launch_bounds__(256) void transpose_w(
    const float* __restrict__ W, unsigned short* __restrict__ WT, int K, int N)
{
  int e = blockIdx.z;
  int k0 = blockIdx.x * 64;
  int n0 = blockIdx.y * 64;
  __shared__ float tile[64][65];
  const float* src = W + (size_t)e * K * N;
  int tid = threadIdx.x;
  int r = tid >> 4;              // 0..15
  int c4 = (tid & 15) * 4;       // 0..60
  #pragma unroll
  for (int j = 0; j < 4; j++){
    int k = r + j * 16;
    float4 v = *(const float4*)(src + (size_t)(k0 + k) * N + n0 + c4);
    tile[k][c4] = v.x; tile[k][c4 + 1] = v.y; tile[k][c4 + 2] = v.z; tile[k][c4 + 3] = v.w;
  }
  __syncthreads();
  unsigned short* dst = WT + (size_t)e * N * K;
  int n = tid >> 2;              // 0..63
  #pragma unroll
  for (int h = 0; h < 2; h++){
    int s = (tid & 3) + h * 4;   // 8-element k-segment 0..7
    unsigned short buf[8];
    #pragma unroll
    for (int j = 0; j < 8; j++) buf[j] = f2bf(tile[s * 8 + j][n]);
    *(s16x8*)(dst + (size_t)(n0 + n) * K + k0 + s * 8) = *(s16x8*)buf;
  }
}

// ---------------- grouped GEMM (m97 structure): C = act(A[group] @ BT^T + bias) ----------------
// 128x128 tile, BK=32, 256 threads (2x2 waves of 64x64), mfma 16x16x32 bf16.
// A: bf16 [T][K] grouped rows. BT: bf16 [E][N][K] (pre-transposed weights).
// Staging via global_load_lds width=16 into unpadded LDS [128][32].
template<int K, int N, int PASS2>
__global__ __launch_bounds__(256) void ffn_gemm(
    const unsigned short* __restrict__ A,
    const unsigned short* __restrict__ BT,
    const float* __restrict__ bias,
    const int* __restrict__ counts, const int* __restrict__ offsets,
    const int* __restrict__ token_of, const float* __restrict__ gw,
    unsigned short* __restrict__ Hout,   // pass1: bf16 gelu output
    float* __restrict__ Fout)            // pass2: fp32 scattered rows, (acc+b2)*w
{
  int e = blockIdx.z;
  int cnt = counts[e];
  int by = blockIdx.y;
  if (by * 128 >= cnt) return;            // uniform early-exit
  int offs = offsets[e];
  int bx = blockIdx.x;
  int tid = threadIdx.x;
  int lane = tid & 63;
  int wv = __builtin_amdgcn_readfirstlane(tid >> 6);
  int wm = wv & 1, wn = wv >> 1;

  __shared__ unsigned short sA[128 * 32];   // 8 KB, NO padding (global_load_lds layout)
  __shared__ unsigned short sB[128 * 32];   // 8 KB

  // Each wave stages 2 chunks of A and 2 of B; chunk = 16 rows x 32 k = 1 KB.
  // Lane i of chunk c: row = c*16 + (i>>2), kseg = (i&3)*8 -> lds byte off = i*16. 
  size_t aoff[2], boff[2];
  unsigned short *aldst[2], *bldst[2];
  #pragma unroll
  for (int j = 0; j < 2; j++){
    int c = 2 * wv + j;
    int row = c * 16 + (lane >> 2);
    int pos = offs + by * 128 + row;
    if (pos > T_TOK - 1) pos = T_TOK - 1;          // clamp; masked at store
    aoff[j] = (size_t)pos * K + (lane & 3) * 8;
    aldst[j] = &sA[c * 512];
    int n = bx * 128 + c * 16 + (lane >> 2);
    boff[j] = ((size_t)e * N + n) * K + (lane & 3) * 8;
    bldst[j] = &sB[c * 512];
  }

  f32x4 accv[4][4];
  #pragma unroll
  for (int mi = 0; mi < 4; mi++)
    #pragma unroll
    for (int ni = 0; ni < 4; ni++) accv[mi][ni] = (f32x4){0.f, 0.f, 0.f, 0.f};

  int col = lane & 15, quad = lane >> 4;
  const int NK = K / 32;
  for (int kt = 0; kt < NK; ++kt){
    __syncthreads();                       // previous tile's LDS reads done
    #pragma unroll
    for (int j = 0; j < 2; j++) gld_lds16(A + aoff[j] + kt * 32, aldst[j]);
    #pragma unroll
    for (int j = 0; j < 2; j++) gld_lds16(BT + boff[j] + kt * 32, bldst[j]);
    __syncthreads();                       // vmcnt(0) drain -> tile visible
    s16x8 af[4], bf[4];
    #pragma unroll
    for (int mi = 0; mi < 4; mi++)
      af[mi] = *(const s16x8*)&sA[(wm * 64 + mi * 16 + col) * 32 + quad * 8];
    #pragma unroll
    for (int ni = 0; ni < 4; ni++)
      bf[ni] = *(const s16x8*)&sB[(wn * 64 + ni * 16 + col) * 32 + quad * 8];
    #pragma unroll
    for (int mi = 0; mi < 4; mi++)
      #pragma unroll
      for (int ni = 0; ni < 4; ni++)
        accv[mi][ni] = __builtin_amdgcn_mfma_f32_16x16x32_bf16(af[mi], bf[ni], accv[mi][ni], 0, 0, 0);
  }

  float bv[4];
  #pragma unroll
  for (int ni = 0; ni < 4; ni++)
    bv[ni] = bias[(size_t)e * N + bx * 128 + wn * 64 + ni * 16 + col];

  if (PASS2 == 0){
    #pragma unroll
    for (int mi = 0; mi < 4; mi++){
      int rbase = by * 128 + wm * 64 + mi * 16 + quad * 4;
      #pragma unroll
      for (int r = 0; r < 4; r++){
        int row = rbase + r;
        if (row < cnt){
          size_t orow = (size_t)(offs + row) * N + bx * 128 + wn * 64 + col;
          #pragma unroll
          for (int ni = 0; ni < 4; ni++){
            float v = accv[mi][ni][r] + bv[ni];
            float g = 0.5f * v * (1.0f + erff(v * 0.70710678118654752f));  // exact gelu
            Hout[orow + ni * 16] = f2bf(g);
          }
        }
      }
    }
  } else {
    #pragma unroll
    for (int mi = 0; mi < 4; mi++){
      int rbase = by * 128 + wm * 64 + mi * 16 + quad * 4;
      #pragma unroll
      for (int r = 0; r < 4; r++){
        int row = rbase + r;
        if (row < cnt){
          int pos = offs + row;
          int tok = token_of[pos];
          float wgt = gw[pos];
          size_t orow = (size_t)tok * N + bx * 128 + wn * 64 + col;
          #pragma unroll
          for (int ni = 0; ni < 4; ni++)
            Fout[orow + ni * 16] = (accv[mi][ni][r] + bv[ni]) * wgt;
        }
      }
    }
  }
}

extern "C" void kernel_launch(void* const* d_in, const int* in_sizes, int n_in,
                              void* d_out, int out_size, void* d_ws, size_t ws_size,
                              hipStream_t stream)
{
  const float* x      = (const float*)d_in[0];
  const float* gumbel = (const float*)d_in[1];
  const float* rw     = (const float*)d_in[2];
  const float* rb     = (const float*)d_in[3];
  const float* w1     = (const float*)d_in[4];
  const float* b1     = (const float*)d_in[5];
  const float* w2     = (const float*)d_in[6];
  const float* b2     = (const float*)d_in[7];
  float* out = (float*)d_out;

  char* ws = (char*)d_ws;
  double* prob_sums = (double*)(ws + 0);     // 64 B
  int* counts    = (int*)(ws + 64);
  int* offsets   = (int*)(ws + 96);
  int* cursor    = (int*)(ws + 128);
  int* expert_id = (int*)(ws + 256);                    // 16 KB
  float* wtok    = (float*)(ws + 256 + 16384);          // 16 KB
  int* token_of  = (int*)(ws + 256 + 2 * 16384);        // 16 KB
  float* gw      = (float*)(ws + 256 + 3 * 16384);      // 16 KB -> ends at 65792
  unsigned short* Xg     = (unsigned short*)(ws + 65792);             // 8 MB bf16
  unsigned short* hidden = (unsigned short*)(ws + 65792 + 8388608);   // 32 MB bf16
  unsigned short* wT     = (unsigned short*)(ws + 65792 + 8388608 + 33554432); // 64 MB, shared w1T/w2T

  hipMemsetAsync(ws, 0, 256, stream);   // zero atomic accumulators (capture-safe)

  router_kernel<<<1024, 256, 0, stream>>>(x, gumbel, rw, rb, expert_id, wtok, prob_sums, counts);
  finalize_kernel<<<1, 64, 0, stream>>>(prob_sums, counts, offsets, cursor, out + 4194304);
  scatter_kernel<<<4096, 256, 0, stream>>>(x, expert_id, wtok, cursor, token_of, gw, Xg);

  // w1T = bf16 transpose of w1: [8][1024][4096] -> [8][4096][1024]
  transpose_w<<<dim3(16, 64, 8), 256, 0, stream>>>(w1, wT, 1024, 4096);
  // hidden = gelu(Xg @ w1[e] + b1[e])   (M=cnt_e, N=4096, K=1024)
  ffn_gemm<1024, 4096, 0><<<dim3(32, 32, 8), 256, 0, stream>>>(
      Xg, wT, b1, counts, offsets, nullptr, nullptr, hidden, nullptr);

  // w2T = bf16 transpose of w2: [8][4096][1024] -> [8][1024][4096]  (reuses wT slab)
  transpose_w<<<dim3(64, 16, 8), 256, 0, stream>>>(w2, wT, 4096, 1024);
  // out[tok] = w_t * (hidden @ w2[e] + b2[e])   (M=cnt_e, N=1024, K=4096)
  ffn_gemm<4096, 1024, 1><<<dim3(8, 32, 8), 256, 0, stream>>>(
      hidden, wT, b2, counts, offsets, token_of, gw, nullptr, out);
}